// Round 7
// baseline (161.525 us; speedup 1.0000x reference)
//
#include <hip/hip_runtime.h>
#include <hip/hip_bf16.h>

// B=2, C=256, N=4096, heads=4, D=64, 3D=192, M_embed=768
#define NH   4
#define D_   64
#define N_   4096
#define C_   256
#define ME   768
#define QSCALE 0.18033688f   // 0.125 * log2(e): softmax done in exp2 domain

typedef float    f32x4  __attribute__((ext_vector_type(4)));
typedef float    f32x16 __attribute__((ext_vector_type(16)));
typedef _Float16 f16x8  __attribute__((ext_vector_type(8)));
typedef _Float16 f16x4  __attribute__((ext_vector_type(4)));

// ---------------------------------------------------------------------------
// Prep: blocks [0,512): x fp32 [b][c][n] -> xT f16 [b][n][c]
//       blocks [512,528): w_out [k][c] -> w_outT f16 [c][k]
// ---------------------------------------------------------------------------
__global__ __launch_bounds__(256) void prep_kernel(const float* __restrict__ x,
                                                   const float* __restrict__ w_out,
                                                   _Float16* __restrict__ xT,
                                                   _Float16* __restrict__ w_outT) {
    __shared__ float T[64][68];
    const int t = threadIdx.x, bx = blockIdx.x;
    if (bx < 512) {
        const int n0 = (bx & 63) * 64, c0 = ((bx >> 6) & 3) * 64, b = bx >> 8;
        const float* xp = x + ((size_t)b * C_ + c0) * N_ + n0;
        #pragma unroll
        for (int r = 0; r < 4; ++r) {
            int idx = r * 256 + t;
            int c = idx >> 4, ng = (idx & 15) * 4;
            *(f32x4*)&T[c][ng] = *(const f32x4*)(xp + (size_t)c * N_ + ng);
        }
        __syncthreads();
        _Float16* dp = xT + ((size_t)b * N_ + n0) * C_ + c0;
        #pragma unroll
        for (int r = 0; r < 2; ++r) {
            int idx = r * 256 + t;
            int n = idx >> 3, cg = (idx & 7) * 8;
            f16x8 v;
            #pragma unroll
            for (int j = 0; j < 8; ++j) v[j] = (_Float16)T[cg + j][n];
            *(f16x8*)(dp + (size_t)n * C_ + cg) = v;
        }
    } else {
        int tile = bx - 512;
        int tc = tile & 3, tk = tile >> 2;
        #pragma unroll
        for (int r = 0; r < 4; ++r) {
            int idx = r * 256 + t;
            int kl = idx >> 4, cl = (idx & 15) * 4;
            *(f32x4*)&T[kl][cl] = *(const f32x4*)(w_out + (size_t)(tk * 64 + kl) * C_ + tc * 64 + cl);
        }
        __syncthreads();
        #pragma unroll
        for (int r = 0; r < 2; ++r) {
            int idx = r * 256 + t;
            int cl = idx >> 3, kg = (idx & 7) * 8;
            f16x8 v;
            #pragma unroll
            for (int j = 0; j < 8; ++j) v[j] = (_Float16)T[kg + j][cl];
            *(f16x8*)(w_outT + (size_t)(tc * 64 + cl) * C_ + tk * 64 + kg) = v;
        }
    }
}

// ---------------------------------------------------------------------------
// QKV GEMM (f16 MFMA 16x16x32). NOW BARRIER-FREE k-loop: both operand
// fragments are contiguous 16B rows in memory, so they stream directly from
// L2 into MFMA registers (w_embed fp32 rows -> cvt; xT f16 rows). No LDS
// staging, no k-loop barriers; compiler pipelines the 8x-unrolled loop.
// Epilogue (unchanged) routes qT/kT [n][d] or vB [d][n]; q pre-scaled.
// ---------------------------------------------------------------------------
__global__ __launch_bounds__(256) void qkv_gemm(const _Float16* __restrict__ xT,
                                                const float* __restrict__ w_embed,
                                                const float* __restrict__ b_embed,
                                                _Float16* __restrict__ qT,
                                                _Float16* __restrict__ kT,
                                                _Float16* __restrict__ vB) {
    __shared__ __align__(16) float Os[64][68];
    const int n0 = blockIdx.x * 64, mt = blockIdx.y, b = blockIdx.z;
    const int m0 = mt * 64;
    const int t = threadIdx.x;
    const int lane = t & 63, w = t >> 6, quad = lane >> 4, l16 = lane & 15;
    const int h = mt / 3, r3 = mt - h * 3;
    const float oscale = (r3 == 0) ? QSCALE : 1.0f;
    const float* arow = w_embed + (size_t)(m0 + w * 16 + l16) * C_ + quad * 8;
    const _Float16* xrow = xT + ((size_t)b * N_ + n0 + l16) * C_ + quad * 8;
    f32x4 acc[4] = {};
    #pragma unroll
    for (int k0 = 0; k0 < C_; k0 += 32) {
        f32x4 a0 = *(const f32x4*)(arow + k0);
        f32x4 a1 = *(const f32x4*)(arow + k0 + 4);
        f16x8 af = { (_Float16)a0[0], (_Float16)a0[1], (_Float16)a0[2], (_Float16)a0[3],
                     (_Float16)a1[0], (_Float16)a1[1], (_Float16)a1[2], (_Float16)a1[3] };
        #pragma unroll
        for (int nb = 0; nb < 4; ++nb) {
            f16x8 bf = *(const f16x8*)(xrow + (size_t)nb * 16 * C_ + k0);
            acc[nb] = __builtin_amdgcn_mfma_f32_16x16x32_f16(af, bf, acc[nb], 0, 0, 0);
        }
    }
    float bias[4];
    #pragma unroll
    for (int rg = 0; rg < 4; ++rg) bias[rg] = b_embed[m0 + w * 16 + quad * 4 + rg];
    #pragma unroll
    for (int nb = 0; nb < 4; ++nb)
        #pragma unroll
        for (int rg = 0; rg < 4; ++rg)
            Os[w * 16 + quad * 4 + rg][nb * 16 + l16] = (acc[nb][rg] + bias[rg]) * oscale;
    __syncthreads();
    const int bh = b * NH + h;
    if (r3 < 2) {
        _Float16* dst = (r3 ? kT : qT) + ((size_t)bh * N_ + n0) * D_;
        #pragma unroll
        for (int r = 0; r < 2; ++r) {
            int idx = r * 256 + t;
            int n = idx >> 3, mg = (idx & 7) * 8;
            f16x8 v;
            #pragma unroll
            for (int j = 0; j < 8; ++j) v[j] = (_Float16)Os[mg + j][n];
            *(f16x8*)(dst + (size_t)n * D_ + mg) = v;
        }
    } else {
        _Float16* dst = vB + (size_t)bh * D_ * N_ + n0;
        #pragma unroll
        for (int r = 0; r < 2; ++r) {
            int idx = r * 256 + t;
            int d = idx >> 3, ng = (idx & 7) * 8;
            f32x4 a = *(const f32x4*)&Os[d][ng];
            f32x4 b2 = *(const f32x4*)&Os[d][ng + 4];
            f16x8 v = { (_Float16)a[0], (_Float16)a[1], (_Float16)a[2], (_Float16)a[3],
                        (_Float16)b2[0], (_Float16)b2[1], (_Float16)b2[2], (_Float16)b2[3] };
            *(f16x8*)(dst + (size_t)d * N_ + ng) = v;
        }
    }
}

// ---------------------------------------------------------------------------
// Flash attention (EXACT r0/r4 verified structure, 54us): St = K*Q^T
// (32x32x16); PV via 32x32x8f16 zero-shuffle; FIXED-M softmax; single-buffer
// K/V LDS; register prefetch; __launch_bounds__(256,4); nsp=4, grid 1024.
// DO NOT restructure: r2 (dbuf+setprio), r3 (nsp=8), r5 (128-thr, spilled)
// all regressed.
// ---------------------------------------------------------------------------
__global__ __launch_bounds__(256, 4) void attn_kernel(const _Float16* __restrict__ qT,
                                                      const _Float16* __restrict__ kT,
                                                      const _Float16* __restrict__ vB,
                                                      _Float16* __restrict__ opart,
                                                      float* __restrict__ mpart,
                                                      float* __restrict__ lpart,
                                                      int splog) {
    __shared__ __align__(16) union SM {
        struct { _Float16 K[64][76], V[64][76]; } s;
        _Float16 Os[128][76];
    } sm;
    const int t = threadIdx.x;
    const int nsp = 1 << splog;
    const int qt = blockIdx.x, h = blockIdx.y;
    const int b = blockIdx.z >> splog, s = blockIdx.z & (nsp - 1);
    const int bh = b * NH + h, sbh = s * 8 + bh;
    const _Float16* kp = kT + (size_t)bh * N_ * D_;
    const _Float16* vp = vB + (size_t)bh * D_ * N_;
    const int lane = t & 63, w = t >> 6, l32 = lane & 31, hl = lane >> 5;
    const int srow = t >> 3, scol = (t & 7) * 8;

    const _Float16* qp = qT + ((size_t)bh * N_ + qt * 128 + w * 32 + l32) * D_;
    f16x8 qf[4];
    #pragma unroll
    for (int kc = 0; kc < 4; ++kc) qf[kc] = *(const f16x8*)(qp + kc * 16 + hl * 8);

    f32x16 oacc0 = {}, oacc1 = {};
    float m_run = 0.f, l_run = 0.f;

    const int niter = 64 >> splog;
    const int jt_lo = s * niter, jt_hi = jt_lo + niter;
    f16x8 kpre[2], vpre[2];
    #pragma unroll
    for (int r = 0; r < 2; ++r) {
        int row = srow + r * 32;
        kpre[r] = *(const f16x8*)(kp + (size_t)(jt_lo * 64 + row) * D_ + scol);
        vpre[r] = *(const f16x8*)(vp + (size_t)row * N_ + jt_lo * 64 + scol);
    }

    for (int jt = jt_lo; jt < jt_hi; ++jt) {
        __syncthreads();
        #pragma unroll
        for (int r = 0; r < 2; ++r) {
            int row = srow + r * 32;
            *(f16x8*)&sm.s.K[row][scol] = kpre[r];
            *(f16x8*)&sm.s.V[row][scol] = vpre[r];
        }
        __syncthreads();
        if (jt + 1 < jt_hi) {
            #pragma unroll
            for (int r = 0; r < 2; ++r) {
                int row = srow + r * 32;
                kpre[r] = *(const f16x8*)(kp + (size_t)((jt + 1) * 64 + row) * D_ + scol);
                vpre[r] = *(const f16x8*)(vp + (size_t)row * N_ + (jt + 1) * 64 + scol);
            }
        }
        f32x16 sa0 = {}, sa1 = {};
        #pragma unroll
        for (int kc = 0; kc < 4; ++kc) {
            f16x8 kf0 = *(const f16x8*)&sm.s.K[l32][kc * 16 + hl * 8];
            sa0 = __builtin_amdgcn_mfma_f32_32x32x16_f16(kf0, qf[kc], sa0, 0, 0, 0);
            f16x8 kf1 = *(const f16x8*)&sm.s.K[32 + l32][kc * 16 + hl * 8];
            sa1 = __builtin_amdgcn_mfma_f32_32x32x16_f16(kf1, qf[kc], sa1, 0, 0, 0);
        }
        if (jt == jt_lo) {
            f32x16 mm;
            #pragma unroll
            for (int r = 0; r < 16; ++r) mm[r] = fmaxf(sa0[r], sa1[r]);
            f32x4 m4;
            #pragma unroll
            for (int r = 0; r < 4; ++r)
                m4[r] = fmaxf(fmaxf(mm[r], mm[r + 4]), fmaxf(mm[r + 8], mm[r + 12]));
            float mx = fmaxf(fmaxf(m4[0], m4[1]), fmaxf(m4[2], m4[3]));
            mx = fmaxf(mx, __shfl_xor(mx, 32));
            m_run = mx + 8.0f;
        }
        #pragma unroll
        for (int r = 0; r < 16; ++r) sa0[r] = __builtin_amdgcn_exp2f(sa0[r] - m_run);
        #pragma unroll
        for (int r = 0; r < 16; ++r) sa1[r] = __builtin_amdgcn_exp2f(sa1[r] - m_run);
        f32x16 sv = sa0 + sa1;
        f32x4 s4;
        #pragma unroll
        for (int r = 0; r < 4; ++r) s4[r] = (sv[r] + sv[r + 4]) + (sv[r + 8] + sv[r + 12]);
        float rs = (s4[0] + s4[1]) + (s4[2] + s4[3]);
        rs += __shfl_xor(rs, 32);
        l_run += rs;
        #pragma unroll
        for (int jb = 0; jb < 2; ++jb) {
            const f32x16& sa = jb ? sa1 : sa0;
            union BU { f16x4 v; int d[2]; } bf[4];
            #pragma unroll
            for (int q = 0; q < 8; ++q)
                bf[q >> 1].d[q & 1] =
                    __builtin_bit_cast(int, __builtin_amdgcn_cvt_pkrtz(sa[2 * q], sa[2 * q + 1]));
            #pragma unroll
            for (int c = 0; c < 4; ++c) {
                const int vcol = jb * 32 + c * 8 + hl * 4;
                f16x4 va = *(const f16x4*)&sm.s.V[l32][vcol];
                oacc0 = __builtin_amdgcn_mfma_f32_32x32x8f16(va, bf[c].v, oacc0, 0, 0, 0);
                f16x4 vb = *(const f16x4*)&sm.s.V[32 + l32][vcol];
                oacc1 = __builtin_amdgcn_mfma_f32_32x32x8f16(vb, bf[c].v, oacc1, 0, 0, 0);
            }
        }
    }
    float linv = 1.f / l_run;
    if (hl == 0) {
        mpart[(size_t)sbh * N_ + qt * 128 + w * 32 + l32] = m_run;
        lpart[(size_t)sbh * N_ + qt * 128 + w * 32 + l32] = l_run;
    }
    __syncthreads();
    #pragma unroll
    for (int db = 0; db < 2; ++db) {
        const f32x16& oc = db ? oacc1 : oacc0;
        #pragma unroll
        for (int rq = 0; rq < 4; ++rq) {
            f16x4 pv = { (_Float16)(oc[rq * 4 + 0] * linv), (_Float16)(oc[rq * 4 + 1] * linv),
                         (_Float16)(oc[rq * 4 + 2] * linv), (_Float16)(oc[rq * 4 + 3] * linv) };
            *(f16x4*)&sm.Os[w * 32 + l32][db * 32 + rq * 8 + hl * 4] = pv;
        }
    }
    __syncthreads();
    _Float16* op = opart + ((size_t)sbh * N_ + qt * 128) * D_;
    #pragma unroll
    for (int r = 0; r < 4; ++r) {
        int idx = r * 256 + t;
        int i = idx >> 3, ch = (idx & 7) * 8;
        *(f16x8*)(op + (size_t)i * D_ + ch) = *(const f16x8*)&sm.Os[i][ch];
    }
}

// ---------------------------------------------------------------------------
// Projection + FUSED combine, n-major, n-tile 32, grid 512 = 2/CU (r4
// verified geometry). NOW BARRIER-FREE k-loop: A fragments stream directly
// from L2-resident w_outT (contiguous f16x8 rows); Y stays in LDS (written
// once in phase 1). No A-staging, no k-loop barriers. Epilogue: bias + x.
// ---------------------------------------------------------------------------
__global__ __launch_bounds__(256) void projc_gemm(const _Float16* __restrict__ opart,
                                                  const float* __restrict__ mpart,
                                                  const float* __restrict__ lpart,
                                                  const _Float16* __restrict__ w_outT,
                                                  const float* __restrict__ b_out,
                                                  const float* __restrict__ x,
                                                  float* __restrict__ out) {
    __shared__ __align__(16) union SMP {
        struct {
            _Float16 Y[32][264];                       // 16896 B (n x k, pad 8)
            float W[4][32][4];                         // 2048 B
        } p;
        float Os[128][36];                             // 18432 B (epilogue)
    } sm;
    const int nt = blockIdx.x, chh = blockIdx.y, b = blockIdx.z;
    const int n0 = nt * 32, c0 = chh * 128;
    const int t = threadIdx.x;
    const int lane = t & 63, w = t >> 6, quad = lane >> 4, l16 = lane & 15;

    // phase 0: combine weights W[h][n][s] for this 32-n strip (threads <128)
    if (t < 128) {
        const int nl = t & 31, hh = t >> 5;
        const int bh = b * NH + hh;
        float mv[4], lv[4];
        #pragma unroll
        for (int sI = 0; sI < 4; ++sI) {
            mv[sI] = mpart[(size_t)(sI * 8 + bh) * N_ + n0 + nl];
            lv[sI] = lpart[(size_t)(sI * 8 + bh) * N_ + n0 + nl];
        }
        float M = fmaxf(fmaxf(mv[0], mv[1]), fmaxf(mv[2], mv[3]));
        float ws[4], sum = 0.f;
        #pragma unroll
        for (int sI = 0; sI < 4; ++sI) {
            ws[sI] = __builtin_amdgcn_exp2f(mv[sI] - M) * lv[sI];
            sum += ws[sI];
        }
        float inv = 1.f / sum;
        #pragma unroll
        for (int sI = 0; sI < 4; ++sI) sm.p.W[hh][nl][sI] = ws[sI] * inv;
    }
    __syncthreads();

    // phase 1: combine 4 split streams -> Y[n][k] f16 (once per block)
    #pragma unroll
    for (int it = 0; it < 4; ++it) {
        int idx = it * 256 + t;
        int n = idx >> 5, kg = (idx & 31) * 8;
        int hh = kg >> 6, d0 = kg & 63;
        const int bh = b * NH + hh;
        const float* Wn = &sm.p.W[hh][n][0];
        float accf[8] = {};
        #pragma unroll
        for (int sI = 0; sI < 4; ++sI) {
            f16x8 ov = *(const f16x8*)(opart + ((size_t)(sI * 8 + bh) * N_ + n0 + n) * D_ + d0);
            float wsv = Wn[sI];
            #pragma unroll
            for (int j = 0; j < 8; ++j) accf[j] += wsv * (float)ov[j];
        }
        f16x8 yv;
        #pragma unroll
        for (int j = 0; j < 8; ++j) yv[j] = (_Float16)accf[j];
        *(f16x8*)&sm.p.Y[n][kg] = yv;
    }
    __syncthreads();

    // phase 2: GEMM 128c x 32n, k over 256; A streams from w_outT, no barriers.
    const _Float16* arow = w_outT + (size_t)(c0 + w * 32 + l16) * C_ + quad * 8;
    f32x4 acc[2][2] = {};
    #pragma unroll
    for (int k0 = 0; k0 < C_; k0 += 32) {
        f16x8 af0 = *(const f16x8*)(arow + k0);
        f16x8 af1 = *(const f16x8*)(arow + (size_t)16 * C_ + k0);
        #pragma unroll
        for (int nb = 0; nb < 2; ++nb) {
            f16x8 bf = *(const f16x8*)&sm.p.Y[nb * 16 + l16][k0 + quad * 8];
            acc[0][nb] = __builtin_amdgcn_mfma_f32_16x16x32_f16(af0, bf, acc[0][nb], 0, 0, 0);
            acc[1][nb] = __builtin_amdgcn_mfma_f32_16x16x32_f16(af1, bf, acc[1][nb], 0, 0, 0);
        }
    }
    __syncthreads();   // all waves done reading Y; Os aliases it
    #pragma unroll
    for (int cb = 0; cb < 2; ++cb)
        #pragma unroll
        for (int nb = 0; nb < 2; ++nb)
            #pragma unroll
            for (int rg = 0; rg < 4; ++rg)
                sm.Os[w * 32 + cb * 16 + quad * 4 + rg][nb * 16 + l16] =
                    acc[cb][nb][rg] + b_out[c0 + w * 32 + cb * 16 + quad * 4 + rg];
    __syncthreads();
    const float* xp = x + ((size_t)b * C_ + c0) * N_ + n0;
    float* op = out + ((size_t)b * C_ + c0) * N_ + n0;
    #pragma unroll
    for (int r = 0; r < 4; ++r) {
        int idx = r * 256 + t;
        int c = idx >> 3, ng = (idx & 7) * 4;
        f32x4 v  = *(const f32x4*)&sm.Os[c][ng];
        f32x4 xv = *(const f32x4*)(xp + (size_t)c * N_ + ng);
        f32x4 o  = { v[0] + xv[0], v[1] + xv[1], v[2] + xv[2], v[3] + xv[3] };
        *(f32x4*)(op + (size_t)c * N_ + ng) = o;
    }
}

// ---------------------------------------------------------------------------
// Workspace (f16 element offsets), nsp=4 (~35 MB):
//   xT 0 (2,097,152) | w_outT 2,293,760 (65,536)
//   qT 2,359,296 | kT 4,456,448 | vB 6,553,600 (2,097,152 each)
//   opart 8,650,752 (8,388,608) | mpart f32 after | lpart after
// ---------------------------------------------------------------------------
extern "C" void kernel_launch(void* const* d_in, const int* in_sizes, int n_in,
                              void* d_out, int out_size, void* d_ws, size_t ws_size,
                              hipStream_t stream) {
    const float* x       = (const float*)d_in[0];
    const float* w_embed = (const float*)d_in[1];
    const float* b_embed = (const float*)d_in[2];
    const float* w_out   = (const float*)d_in[3];
    const float* b_out   = (const float*)d_in[4];
    float* out = (float*)d_out;

    const int splog = 2;   // nsp=4: attn grid 1024 = 4 blocks/CU

    _Float16* base   = (_Float16*)d_ws;
    _Float16* xT     = base;
    _Float16* w_outT = base + 2293760;
    _Float16* qT     = base + 2359296;
    _Float16* kT     = base + 4456448;
    _Float16* vB     = base + 6553600;
    _Float16* opart  = base + 8650752;
    float*    mpart  = (float*)(opart + (size_t)4 * 8 * N_ * D_);
    float*    lpart  = mpart + (size_t)4 * 8 * N_;

    prep_kernel<<<dim3(528, 1, 1), 256, 0, stream>>>(x, w_out, xT, w_outT);
    qkv_gemm   <<<dim3(64, 12, 2), 256, 0, stream>>>(xT, w_embed, b_embed, qT, kT, vB);
    attn_kernel<<<dim3(32, 4, 2 << splog), 256, 0, stream>>>(qT, kT, vB, opart, mpart, lpart, splog);
    projc_gemm <<<dim3(128, 2, 2), 256, 0, stream>>>(opart, mpart, lpart, w_outT, b_out, x, out);
}

// Round 8
// 148.613 us; speedup vs baseline: 1.0869x; 1.0869x over previous
//
#include <hip/hip_runtime.h>
#include <hip/hip_bf16.h>

// B=2, C=256, N=4096, heads=4, D=64, 3D=192, M_embed=768
#define NH   4
#define D_   64
#define N_   4096
#define C_   256
#define ME   768
#define QSCALE 0.18033688f   // 0.125 * log2(e): softmax done in exp2 domain

typedef float    f32x4  __attribute__((ext_vector_type(4)));
typedef float    f32x16 __attribute__((ext_vector_type(16)));
typedef _Float16 f16x8  __attribute__((ext_vector_type(8)));
typedef _Float16 f16x4  __attribute__((ext_vector_type(4)));

// ---------------------------------------------------------------------------
// Prep (w_out ONLY now; x-transpose moved into qkv): 16 blocks.
// w_out [k][c] -> w_outT f16 [c][k]
// ---------------------------------------------------------------------------
__global__ __launch_bounds__(256) void prep_kernel(const float* __restrict__ w_out,
                                                   _Float16* __restrict__ w_outT) {
    __shared__ float T[64][68];
    const int t = threadIdx.x, tile = blockIdx.x;
    const int tc = tile & 3, tk = tile >> 2;
    #pragma unroll
    for (int r = 0; r < 4; ++r) {
        int idx = r * 256 + t;
        int kl = idx >> 4, cl = (idx & 15) * 4;
        *(f32x4*)&T[kl][cl] = *(const f32x4*)(w_out + (size_t)(tk * 64 + kl) * C_ + tc * 64 + cl);
    }
    __syncthreads();
    #pragma unroll
    for (int r = 0; r < 2; ++r) {
        int idx = r * 256 + t;
        int cl = idx >> 3, kg = (idx & 7) * 8;
        f16x8 v;
        #pragma unroll
        for (int j = 0; j < 8; ++j) v[j] = (_Float16)T[kg + j][cl];
        *(f16x8*)(w_outT + (size_t)(tc * 64 + cl) * C_ + tk * 64 + kg) = v;
    }
}

// ---------------------------------------------------------------------------
// QKV GEMM (f16 MFMA 16x16x32). Double-buffered staging, one barrier per
// K-step (r4 verified). NEW: reads x fp32 [b][c][n] DIRECTLY (no xT): the
// X-tile is loaded coalesced in native layout (f32x4 per lane, 256B/16-lane
// segments) and written TRANSPOSED into LDS as scalars. X row = 38 f16
// (76B = 19 dwords, gcd(19,32)=1 -> transposed writes spread across banks;
// same odd-stride trick as attn's verified K[64][76]). A-side unchanged.
// Epilogue routes qT/kT [n][d] or vB [d][n]; q pre-scaled by QSCALE.
// ---------------------------------------------------------------------------
__global__ __launch_bounds__(256) void qkv_gemm(const float* __restrict__ x,
                                                const float* __restrict__ w_embed,
                                                const float* __restrict__ b_embed,
                                                _Float16* __restrict__ qT,
                                                _Float16* __restrict__ kT,
                                                _Float16* __restrict__ vB) {
    __shared__ __align__(16) union SM {
        struct { _Float16 A[2][64][40], X[2][64][38]; } s;   // 19968 B
        float Os[64][68];                                     // 17408 B
    } sm;
    const int n0 = blockIdx.x * 64, mt = blockIdx.y, b = blockIdx.z;
    const int m0 = mt * 64;
    const int t = threadIdx.x;
    const int lane = t & 63, w = t >> 6, quad = lane >> 4, l16 = lane & 15;
    const int srow = t >> 2, skoff = (t & 3) * 8;     // A stage map (r4)
    const int xc = t >> 4, xn = (t & 15) * 4;         // X stage: c-row, n*4
    const int h = mt / 3, r3 = mt - h * 3;
    const float oscale = (r3 == 0) ? QSCALE : 1.0f;
    const float* ap = w_embed + (size_t)(m0 + srow) * C_ + skoff;
    const float* xp = x + (size_t)b * C_ * N_ + n0 + xn;   // + c*N_ per row
    f32x4 a0pre = *(const f32x4*)(ap);
    f32x4 a1pre = *(const f32x4*)(ap + 4);
    f32x4 xpre0 = *(const f32x4*)(xp + (size_t)(xc) * N_);
    f32x4 xpre1 = *(const f32x4*)(xp + (size_t)(16 + xc) * N_);
    f32x4 acc[4] = {};
    int cur = 0;
    for (int k0 = 0; k0 < C_; k0 += 32, cur ^= 1) {
        {
            f16x8 av = { (_Float16)a0pre[0], (_Float16)a0pre[1], (_Float16)a0pre[2], (_Float16)a0pre[3],
                         (_Float16)a1pre[0], (_Float16)a1pre[1], (_Float16)a1pre[2], (_Float16)a1pre[3] };
            *(f16x8*)&sm.s.A[cur][srow][skoff] = av;
            #pragma unroll
            for (int j = 0; j < 4; ++j) {
                sm.s.X[cur][xn + j][xc]      = (_Float16)xpre0[j];
                sm.s.X[cur][xn + j][16 + xc] = (_Float16)xpre1[j];
            }
        }
        __syncthreads();
        if (k0 + 32 < C_) {
            a0pre = *(const f32x4*)(ap + k0 + 32);
            a1pre = *(const f32x4*)(ap + k0 + 36);
            xpre0 = *(const f32x4*)(xp + (size_t)(k0 + 32 + xc) * N_);
            xpre1 = *(const f32x4*)(xp + (size_t)(k0 + 48 + xc) * N_);
        }
        f16x8 af = *(const f16x8*)&sm.s.A[cur][w * 16 + l16][quad * 8];
        #pragma unroll
        for (int nb = 0; nb < 4; ++nb) {
            f16x8 bf = *(const f16x8*)&sm.s.X[cur][nb * 16 + l16][quad * 8];
            acc[nb] = __builtin_amdgcn_mfma_f32_16x16x32_f16(af, bf, acc[nb], 0, 0, 0);
        }
    }
    float bias[4];
    #pragma unroll
    for (int rg = 0; rg < 4; ++rg) bias[rg] = b_embed[m0 + w * 16 + quad * 4 + rg];
    __syncthreads();
    #pragma unroll
    for (int nb = 0; nb < 4; ++nb)
        #pragma unroll
        for (int rg = 0; rg < 4; ++rg)
            sm.Os[w * 16 + quad * 4 + rg][nb * 16 + l16] = (acc[nb][rg] + bias[rg]) * oscale;
    __syncthreads();
    const int bh = b * NH + h;
    if (r3 < 2) {
        _Float16* dst = (r3 ? kT : qT) + ((size_t)bh * N_ + n0) * D_;
        #pragma unroll
        for (int r = 0; r < 2; ++r) {
            int idx = r * 256 + t;
            int n = idx >> 3, mg = (idx & 7) * 8;
            f16x8 v;
            #pragma unroll
            for (int j = 0; j < 8; ++j) v[j] = (_Float16)sm.Os[mg + j][n];
            *(f16x8*)(dst + (size_t)n * D_ + mg) = v;
        }
    } else {
        _Float16* dst = vB + (size_t)bh * D_ * N_ + n0;
        #pragma unroll
        for (int r = 0; r < 2; ++r) {
            int idx = r * 256 + t;
            int d = idx >> 3, ng = (idx & 7) * 8;
            f32x4 a = *(const f32x4*)&sm.Os[d][ng];
            f32x4 b2 = *(const f32x4*)&sm.Os[d][ng + 4];
            f16x8 v = { (_Float16)a[0], (_Float16)a[1], (_Float16)a[2], (_Float16)a[3],
                        (_Float16)b2[0], (_Float16)b2[1], (_Float16)b2[2], (_Float16)b2[3] };
            *(f16x8*)(dst + (size_t)d * N_ + ng) = v;
        }
    }
}

// ---------------------------------------------------------------------------
// Flash attention (EXACT r0/r4 verified structure, 54us): St = K*Q^T
// (32x32x16); PV via 32x32x8f16 zero-shuffle; FIXED-M softmax; single-buffer
// K/V LDS; register prefetch; __launch_bounds__(256,4); nsp=4, grid 1024.
// DO NOT restructure: r2 (dbuf+setprio), r3 (nsp=8), r5 (128-thr, spilled),
// r7 (barrier-free GEMMs) all regressed.
// ---------------------------------------------------------------------------
__global__ __launch_bounds__(256, 4) void attn_kernel(const _Float16* __restrict__ qT,
                                                      const _Float16* __restrict__ kT,
                                                      const _Float16* __restrict__ vB,
                                                      _Float16* __restrict__ opart,
                                                      float* __restrict__ mpart,
                                                      float* __restrict__ lpart,
                                                      int splog) {
    __shared__ __align__(16) union SM {
        struct { _Float16 K[64][76], V[64][76]; } s;
        _Float16 Os[128][76];
    } sm;
    const int t = threadIdx.x;
    const int nsp = 1 << splog;
    const int qt = blockIdx.x, h = blockIdx.y;
    const int b = blockIdx.z >> splog, s = blockIdx.z & (nsp - 1);
    const int bh = b * NH + h, sbh = s * 8 + bh;
    const _Float16* kp = kT + (size_t)bh * N_ * D_;
    const _Float16* vp = vB + (size_t)bh * D_ * N_;
    const int lane = t & 63, w = t >> 6, l32 = lane & 31, hl = lane >> 5;
    const int srow = t >> 3, scol = (t & 7) * 8;

    const _Float16* qp = qT + ((size_t)bh * N_ + qt * 128 + w * 32 + l32) * D_;
    f16x8 qf[4];
    #pragma unroll
    for (int kc = 0; kc < 4; ++kc) qf[kc] = *(const f16x8*)(qp + kc * 16 + hl * 8);

    f32x16 oacc0 = {}, oacc1 = {};
    float m_run = 0.f, l_run = 0.f;

    const int niter = 64 >> splog;
    const int jt_lo = s * niter, jt_hi = jt_lo + niter;
    f16x8 kpre[2], vpre[2];
    #pragma unroll
    for (int r = 0; r < 2; ++r) {
        int row = srow + r * 32;
        kpre[r] = *(const f16x8*)(kp + (size_t)(jt_lo * 64 + row) * D_ + scol);
        vpre[r] = *(const f16x8*)(vp + (size_t)row * N_ + jt_lo * 64 + scol);
    }

    for (int jt = jt_lo; jt < jt_hi; ++jt) {
        __syncthreads();
        #pragma unroll
        for (int r = 0; r < 2; ++r) {
            int row = srow + r * 32;
            *(f16x8*)&sm.s.K[row][scol] = kpre[r];
            *(f16x8*)&sm.s.V[row][scol] = vpre[r];
        }
        __syncthreads();
        if (jt + 1 < jt_hi) {
            #pragma unroll
            for (int r = 0; r < 2; ++r) {
                int row = srow + r * 32;
                kpre[r] = *(const f16x8*)(kp + (size_t)((jt + 1) * 64 + row) * D_ + scol);
                vpre[r] = *(const f16x8*)(vp + (size_t)row * N_ + (jt + 1) * 64 + scol);
            }
        }
        f32x16 sa0 = {}, sa1 = {};
        #pragma unroll
        for (int kc = 0; kc < 4; ++kc) {
            f16x8 kf0 = *(const f16x8*)&sm.s.K[l32][kc * 16 + hl * 8];
            sa0 = __builtin_amdgcn_mfma_f32_32x32x16_f16(kf0, qf[kc], sa0, 0, 0, 0);
            f16x8 kf1 = *(const f16x8*)&sm.s.K[32 + l32][kc * 16 + hl * 8];
            sa1 = __builtin_amdgcn_mfma_f32_32x32x16_f16(kf1, qf[kc], sa1, 0, 0, 0);
        }
        if (jt == jt_lo) {
            f32x16 mm;
            #pragma unroll
            for (int r = 0; r < 16; ++r) mm[r] = fmaxf(sa0[r], sa1[r]);
            f32x4 m4;
            #pragma unroll
            for (int r = 0; r < 4; ++r)
                m4[r] = fmaxf(fmaxf(mm[r], mm[r + 4]), fmaxf(mm[r + 8], mm[r + 12]));
            float mx = fmaxf(fmaxf(m4[0], m4[1]), fmaxf(m4[2], m4[3]));
            mx = fmaxf(mx, __shfl_xor(mx, 32));
            m_run = mx + 8.0f;
        }
        #pragma unroll
        for (int r = 0; r < 16; ++r) sa0[r] = __builtin_amdgcn_exp2f(sa0[r] - m_run);
        #pragma unroll
        for (int r = 0; r < 16; ++r) sa1[r] = __builtin_amdgcn_exp2f(sa1[r] - m_run);
        f32x16 sv = sa0 + sa1;
        f32x4 s4;
        #pragma unroll
        for (int r = 0; r < 4; ++r) s4[r] = (sv[r] + sv[r + 4]) + (sv[r + 8] + sv[r + 12]);
        float rs = (s4[0] + s4[1]) + (s4[2] + s4[3]);
        rs += __shfl_xor(rs, 32);
        l_run += rs;
        #pragma unroll
        for (int jb = 0; jb < 2; ++jb) {
            const f32x16& sa = jb ? sa1 : sa0;
            union BU { f16x4 v; int d[2]; } bf[4];
            #pragma unroll
            for (int q = 0; q < 8; ++q)
                bf[q >> 1].d[q & 1] =
                    __builtin_bit_cast(int, __builtin_amdgcn_cvt_pkrtz(sa[2 * q], sa[2 * q + 1]));
            #pragma unroll
            for (int c = 0; c < 4; ++c) {
                const int vcol = jb * 32 + c * 8 + hl * 4;
                f16x4 va = *(const f16x4*)&sm.s.V[l32][vcol];
                oacc0 = __builtin_amdgcn_mfma_f32_32x32x8f16(va, bf[c].v, oacc0, 0, 0, 0);
                f16x4 vb = *(const f16x4*)&sm.s.V[32 + l32][vcol];
                oacc1 = __builtin_amdgcn_mfma_f32_32x32x8f16(vb, bf[c].v, oacc1, 0, 0, 0);
            }
        }
    }
    float linv = 1.f / l_run;
    if (hl == 0) {
        mpart[(size_t)sbh * N_ + qt * 128 + w * 32 + l32] = m_run;
        lpart[(size_t)sbh * N_ + qt * 128 + w * 32 + l32] = l_run;
    }
    __syncthreads();
    #pragma unroll
    for (int db = 0; db < 2; ++db) {
        const f32x16& oc = db ? oacc1 : oacc0;
        #pragma unroll
        for (int rq = 0; rq < 4; ++rq) {
            f16x4 pv = { (_Float16)(oc[rq * 4 + 0] * linv), (_Float16)(oc[rq * 4 + 1] * linv),
                         (_Float16)(oc[rq * 4 + 2] * linv), (_Float16)(oc[rq * 4 + 3] * linv) };
            *(f16x4*)&sm.Os[w * 32 + l32][db * 32 + rq * 8 + hl * 4] = pv;
        }
    }
    __syncthreads();
    _Float16* op = opart + ((size_t)sbh * N_ + qt * 128) * D_;
    #pragma unroll
    for (int r = 0; r < 4; ++r) {
        int idx = r * 256 + t;
        int i = idx >> 3, ch = (idx & 7) * 8;
        *(f16x8*)(op + (size_t)i * D_ + ch) = *(const f16x8*)&sm.Os[i][ch];
    }
}

// ---------------------------------------------------------------------------
// Projection + FUSED combine (EXACT r4 verified, 138.5us config): n-major,
// n-tile 32, block = [128 c x 32 n]; grid(128,2,2) = 512 = 2/CU; staged A
// with 2 barriers per k-step. Epilogue: bias + x.
// ---------------------------------------------------------------------------
__global__ __launch_bounds__(256) void projc_gemm(const _Float16* __restrict__ opart,
                                                  const float* __restrict__ mpart,
                                                  const float* __restrict__ lpart,
                                                  const _Float16* __restrict__ w_outT,
                                                  const float* __restrict__ b_out,
                                                  const float* __restrict__ x,
                                                  float* __restrict__ out) {
    __shared__ __align__(16) union SMP {
        struct {
            _Float16 Y[32][264];                       // 16896 B (n x k, pad 8)
            union { float W[4][32][4]; _Float16 A[128][40]; } u;  // 10240 B
        } p;
        float Os[128][36];                             // 18432 B (epilogue)
    } sm;
    const int nt = blockIdx.x, chh = blockIdx.y, b = blockIdx.z;
    const int n0 = nt * 32, c0 = chh * 128;
    const int t = threadIdx.x;
    const int lane = t & 63, w = t >> 6, quad = lane >> 4, l16 = lane & 15;

    // phase 0: combine weights W[h][n][s] for this 32-n strip (threads <128)
    if (t < 128) {
        const int nl = t & 31, hh = t >> 5;
        const int bh = b * NH + hh;
        float mv[4], lv[4];
        #pragma unroll
        for (int sI = 0; sI < 4; ++sI) {
            mv[sI] = mpart[(size_t)(sI * 8 + bh) * N_ + n0 + nl];
            lv[sI] = lpart[(size_t)(sI * 8 + bh) * N_ + n0 + nl];
        }
        float M = fmaxf(fmaxf(mv[0], mv[1]), fmaxf(mv[2], mv[3]));
        float ws[4], sum = 0.f;
        #pragma unroll
        for (int sI = 0; sI < 4; ++sI) {
            ws[sI] = __builtin_amdgcn_exp2f(mv[sI] - M) * lv[sI];
            sum += ws[sI];
        }
        float inv = 1.f / sum;
        #pragma unroll
        for (int sI = 0; sI < 4; ++sI) sm.p.u.W[hh][nl][sI] = ws[sI] * inv;
    }
    __syncthreads();

    // phase 1: combine 4 split streams -> Y[n][k] f16 (once per block)
    #pragma unroll
    for (int it = 0; it < 4; ++it) {
        int idx = it * 256 + t;
        int n = idx >> 5, kg = (idx & 31) * 8;
        int hh = kg >> 6, d0 = kg & 63;
        const int bh = b * NH + hh;
        const float* Wn = &sm.p.u.W[hh][n][0];
        float accf[8] = {};
        #pragma unroll
        for (int sI = 0; sI < 4; ++sI) {
            f16x8 ov = *(const f16x8*)(opart + ((size_t)(sI * 8 + bh) * N_ + n0 + n) * D_ + d0);
            float wsv = Wn[sI];
            #pragma unroll
            for (int j = 0; j < 8; ++j) accf[j] += wsv * (float)ov[j];
        }
        f16x8 yv;
        #pragma unroll
        for (int j = 0; j < 8; ++j) yv[j] = (_Float16)accf[j];
        *(f16x8*)&sm.p.Y[n][kg] = yv;
    }
    __syncthreads();

    // phase 2: GEMM: 128c x 32n, k-loop over 256. Wave w owns c-blocks 2w,2w+1.
    const int srow = t >> 1, skoff = (t & 1) * 16;   // A stage: 128 rows x 32 k
    const _Float16* ap = w_outT + (size_t)(c0 + srow) * C_ + skoff;
    f16x8 apre0 = *(const f16x8*)(ap);
    f16x8 apre1 = *(const f16x8*)(ap + 8);
    f32x4 acc[2][2] = {};
    for (int k0 = 0; k0 < C_; k0 += 32) {
        __syncthreads();
        *(f16x8*)&sm.p.u.A[srow][skoff]     = apre0;
        *(f16x8*)&sm.p.u.A[srow][skoff + 8] = apre1;
        __syncthreads();
        if (k0 + 32 < C_) {
            apre0 = *(const f16x8*)(ap + k0 + 32);
            apre1 = *(const f16x8*)(ap + k0 + 40);
        }
        #pragma unroll
        for (int cb = 0; cb < 2; ++cb) {
            f16x8 af = *(const f16x8*)&sm.p.u.A[w * 32 + cb * 16 + l16][quad * 8];
            #pragma unroll
            for (int nb = 0; nb < 2; ++nb) {
                f16x8 bf = *(const f16x8*)&sm.p.Y[nb * 16 + l16][k0 + quad * 8];
                acc[cb][nb] = __builtin_amdgcn_mfma_f32_16x16x32_f16(af, bf, acc[cb][nb], 0, 0, 0);
            }
        }
    }
    __syncthreads();   // Y/A dead; Os aliases them
    #pragma unroll
    for (int cb = 0; cb < 2; ++cb)
        #pragma unroll
        for (int nb = 0; nb < 2; ++nb)
            #pragma unroll
            for (int rg = 0; rg < 4; ++rg)
                sm.Os[w * 32 + cb * 16 + quad * 4 + rg][nb * 16 + l16] =
                    acc[cb][nb][rg] + b_out[c0 + w * 32 + cb * 16 + quad * 4 + rg];
    __syncthreads();
    const float* xp = x + ((size_t)b * C_ + c0) * N_ + n0;
    float* op = out + ((size_t)b * C_ + c0) * N_ + n0;
    #pragma unroll
    for (int r = 0; r < 4; ++r) {
        int idx = r * 256 + t;
        int c = idx >> 3, ng = (idx & 7) * 4;
        f32x4 v  = *(const f32x4*)&sm.Os[c][ng];
        f32x4 xv = *(const f32x4*)(xp + (size_t)c * N_ + ng);
        f32x4 o  = { v[0] + xv[0], v[1] + xv[1], v[2] + xv[2], v[3] + xv[3] };
        *(f32x4*)(op + (size_t)c * N_ + ng) = o;
    }
}

// ---------------------------------------------------------------------------
// Workspace (f16 element offsets), nsp=4 (~35 MB; xT slot now unused):
//   w_outT 2,293,760 (65,536)
//   qT 2,359,296 | kT 4,456,448 | vB 6,553,600 (2,097,152 each)
//   opart 8,650,752 (8,388,608) | mpart f32 after | lpart after
// ---------------------------------------------------------------------------
extern "C" void kernel_launch(void* const* d_in, const int* in_sizes, int n_in,
                              void* d_out, int out_size, void* d_ws, size_t ws_size,
                              hipStream_t stream) {
    const float* x       = (const float*)d_in[0];
    const float* w_embed = (const float*)d_in[1];
    const float* b_embed = (const float*)d_in[2];
    const float* w_out   = (const float*)d_in[3];
    const float* b_out   = (const float*)d_in[4];
    float* out = (float*)d_out;

    const int splog = 2;   // nsp=4: attn grid 1024 = 4 blocks/CU

    _Float16* base   = (_Float16*)d_ws;
    _Float16* w_outT = base + 2293760;
    _Float16* qT     = base + 2359296;
    _Float16* kT     = base + 4456448;
    _Float16* vB     = base + 6553600;
    _Float16* opart  = base + 8650752;
    float*    mpart  = (float*)(opart + (size_t)4 * 8 * N_ * D_);
    float*    lpart  = mpart + (size_t)4 * 8 * N_;

    prep_kernel<<<dim3(16, 1, 1),  256, 0, stream>>>(w_out, w_outT);
    qkv_gemm   <<<dim3(64, 12, 2), 256, 0, stream>>>(x, w_embed, b_embed, qT, kT, vB);
    attn_kernel<<<dim3(32, 4, 2 << splog), 256, 0, stream>>>(qT, kT, vB, opart, mpart, lpart, splog);
    projc_gemm <<<dim3(128, 2, 2), 256, 0, stream>>>(opart, mpart, lpart, w_outT, b_out, x, out);
}

// Round 9
// 137.548 us; speedup vs baseline: 1.1743x; 1.0804x over previous
//
#include <hip/hip_runtime.h>
#include <hip/hip_bf16.h>

// B=2, C=256, N=4096, heads=4, D=64, 3D=192, M_embed=768
#define NH   4
#define D_   64
#define N_   4096
#define C_   256
#define ME   768
#define QSCALE 0.18033688f   // 0.125 * log2(e): softmax done in exp2 domain

typedef float    f32x4  __attribute__((ext_vector_type(4)));
typedef float    f32x16 __attribute__((ext_vector_type(16)));
typedef _Float16 f16x8  __attribute__((ext_vector_type(8)));
typedef _Float16 f16x4  __attribute__((ext_vector_type(4)));

// ---------------------------------------------------------------------------
// Prep: blocks [0,512): x fp32 [b][c][n] -> xT f16 [b][n][c]
//       blocks [512,528): w_out [k][c] -> w_outT f16 [c][k]
// (r4 verified; r8 showed fusing the x-transpose into qkv is 12x redundant)
// ---------------------------------------------------------------------------
__global__ __launch_bounds__(256) void prep_kernel(const float* __restrict__ x,
                                                   const float* __restrict__ w_out,
                                                   _Float16* __restrict__ xT,
                                                   _Float16* __restrict__ w_outT) {
    __shared__ float T[64][68];
    const int t = threadIdx.x, bx = blockIdx.x;
    if (bx < 512) {
        const int n0 = (bx & 63) * 64, c0 = ((bx >> 6) & 3) * 64, b = bx >> 8;
        const float* xp = x + ((size_t)b * C_ + c0) * N_ + n0;
        #pragma unroll
        for (int r = 0; r < 4; ++r) {
            int idx = r * 256 + t;
            int c = idx >> 4, ng = (idx & 15) * 4;
            *(f32x4*)&T[c][ng] = *(const f32x4*)(xp + (size_t)c * N_ + ng);
        }
        __syncthreads();
        _Float16* dp = xT + ((size_t)b * N_ + n0) * C_ + c0;
        #pragma unroll
        for (int r = 0; r < 2; ++r) {
            int idx = r * 256 + t;
            int n = idx >> 3, cg = (idx & 7) * 8;
            f16x8 v;
            #pragma unroll
            for (int j = 0; j < 8; ++j) v[j] = (_Float16)T[cg + j][n];
            *(f16x8*)(dp + (size_t)n * C_ + cg) = v;
        }
    } else {
        int tile = bx - 512;
        int tc = tile & 3, tk = tile >> 2;
        #pragma unroll
        for (int r = 0; r < 4; ++r) {
            int idx = r * 256 + t;
            int kl = idx >> 4, cl = (idx & 15) * 4;
            *(f32x4*)&T[kl][cl] = *(const f32x4*)(w_out + (size_t)(tk * 64 + kl) * C_ + tc * 64 + cl);
        }
        __syncthreads();
        #pragma unroll
        for (int r = 0; r < 2; ++r) {
            int idx = r * 256 + t;
            int cl = idx >> 3, kg = (idx & 7) * 8;
            f16x8 v;
            #pragma unroll
            for (int j = 0; j < 8; ++j) v[j] = (_Float16)T[kg + j][cl];
            *(f16x8*)(w_outT + (size_t)(tc * 64 + cl) * C_ + tk * 64 + kg) = v;
        }
    }
}

// ---------------------------------------------------------------------------
// QKV GEMM (f16 MFMA 16x16x32). Double-buffered A/X staging, one barrier per
// K-step (r4 verified). Epilogue routes qT/kT [n][d] or vB [d][n]; q
// pre-scaled by QSCALE.
// ---------------------------------------------------------------------------
__global__ __launch_bounds__(256) void qkv_gemm(const _Float16* __restrict__ xT,
                                                const float* __restrict__ w_embed,
                                                const float* __restrict__ b_embed,
                                                _Float16* __restrict__ qT,
                                                _Float16* __restrict__ kT,
                                                _Float16* __restrict__ vB) {
    __shared__ __align__(16) union SM {
        struct { _Float16 A[2][64][40], X[2][64][40]; } s;   // 20480 B
        float Os[64][68];                                     // 17408 B
    } sm;
    const int n0 = blockIdx.x * 64, mt = blockIdx.y, b = blockIdx.z;
    const int m0 = mt * 64;
    const int t = threadIdx.x;
    const int lane = t & 63, w = t >> 6, quad = lane >> 4, l16 = lane & 15;
    const int srow = t >> 2, skoff = (t & 3) * 8;
    const int h = mt / 3, r3 = mt - h * 3;
    const float oscale = (r3 == 0) ? QSCALE : 1.0f;
    const float* ap = w_embed + (size_t)(m0 + srow) * C_ + skoff;
    const _Float16* xp = xT + ((size_t)b * N_ + n0 + srow) * C_ + skoff;
    f32x4 a0pre = *(const f32x4*)(ap);
    f32x4 a1pre = *(const f32x4*)(ap + 4);
    f16x8 xpre  = *(const f16x8*)(xp);
    f32x4 acc[4] = {};
    int cur = 0;
    for (int k0 = 0; k0 < C_; k0 += 32, cur ^= 1) {
        {
            f16x8 av = { (_Float16)a0pre[0], (_Float16)a0pre[1], (_Float16)a0pre[2], (_Float16)a0pre[3],
                         (_Float16)a1pre[0], (_Float16)a1pre[1], (_Float16)a1pre[2], (_Float16)a1pre[3] };
            *(f16x8*)&sm.s.A[cur][srow][skoff] = av;
            *(f16x8*)&sm.s.X[cur][srow][skoff] = xpre;
        }
        __syncthreads();
        if (k0 + 32 < C_) {
            a0pre = *(const f32x4*)(ap + k0 + 32);
            a1pre = *(const f32x4*)(ap + k0 + 36);
            xpre  = *(const f16x8*)(xp + k0 + 32);
        }
        f16x8 af = *(const f16x8*)&sm.s.A[cur][w * 16 + l16][quad * 8];
        #pragma unroll
        for (int nb = 0; nb < 4; ++nb) {
            f16x8 bf = *(const f16x8*)&sm.s.X[cur][nb * 16 + l16][quad * 8];
            acc[nb] = __builtin_amdgcn_mfma_f32_16x16x32_f16(af, bf, acc[nb], 0, 0, 0);
        }
    }
    float bias[4];
    #pragma unroll
    for (int rg = 0; rg < 4; ++rg) bias[rg] = b_embed[m0 + w * 16 + quad * 4 + rg];
    __syncthreads();
    #pragma unroll
    for (int nb = 0; nb < 4; ++nb)
        #pragma unroll
        for (int rg = 0; rg < 4; ++rg)
            sm.Os[w * 16 + quad * 4 + rg][nb * 16 + l16] = (acc[nb][rg] + bias[rg]) * oscale;
    __syncthreads();
    const int bh = b * NH + h;
    if (r3 < 2) {
        _Float16* dst = (r3 ? kT : qT) + ((size_t)bh * N_ + n0) * D_;
        #pragma unroll
        for (int r = 0; r < 2; ++r) {
            int idx = r * 256 + t;
            int n = idx >> 3, mg = (idx & 7) * 8;
            f16x8 v;
            #pragma unroll
            for (int j = 0; j < 8; ++j) v[j] = (_Float16)sm.Os[mg + j][n];
            *(f16x8*)(dst + (size_t)n * D_ + mg) = v;
        }
    } else {
        _Float16* dst = vB + (size_t)bh * D_ * N_ + n0;
        #pragma unroll
        for (int r = 0; r < 2; ++r) {
            int idx = r * 256 + t;
            int d = idx >> 3, ng = (idx & 7) * 8;
            f32x4 a = *(const f32x4*)&sm.Os[d][ng];
            f32x4 b2 = *(const f32x4*)&sm.Os[d][ng + 4];
            f16x8 v = { (_Float16)a[0], (_Float16)a[1], (_Float16)a[2], (_Float16)a[3],
                        (_Float16)b2[0], (_Float16)b2[1], (_Float16)b2[2], (_Float16)b2[3] };
            *(f16x8*)(dst + (size_t)d * N_ + ng) = v;
        }
    }
}

// ---------------------------------------------------------------------------
// Flash attention (r0/r4 verified math/structure, 54us). ONLY change: flat
// grid + XCD-aware block decode. The 32 qt-blocks sharing one (h,b,s) K/V
// quarter now land on ONE XCD (group g = bid&7 + 8*(slot>>5)), so K/V become
// L2-resident per XCD (4 groups x 256KB = 1MB << 4MB) instead of each XCD
// refetching from HBM (FETCH was 37.4MB vs 6.3MB ideal = 6x overfetch).
// DO NOT restructure the loop: r2 (dbuf+setprio), r3 (nsp=8), r5 (128-thr,
// spilled), r7 (barrier-free GEMMs) all regressed.
// ---------------------------------------------------------------------------
__global__ __launch_bounds__(256, 4) void attn_kernel(const _Float16* __restrict__ qT,
                                                      const _Float16* __restrict__ kT,
                                                      const _Float16* __restrict__ vB,
                                                      _Float16* __restrict__ opart,
                                                      float* __restrict__ mpart,
                                                      float* __restrict__ lpart,
                                                      int splog) {
    __shared__ __align__(16) union SM {
        struct { _Float16 K[64][76], V[64][76]; } s;
        _Float16 Os[128][76];
    } sm;
    const int t = threadIdx.x;
    const int nsp = 1 << splog;
    // XCD-aware decode: bid in [0,1024). xcd = bid&7; slot = bid>>3;
    // qt = slot&31; gg = slot>>5 in [0,4); g = xcd + 8*gg in [0,32);
    // h = g&3; bz = g>>2 in [0,8).
    const int bid = blockIdx.x;
    const int xcd = bid & 7, slot = bid >> 3;
    const int qt = slot & 31;
    const int g = xcd + 8 * (slot >> 5);
    const int h = g & 3, bz = g >> 2;
    const int b = bz >> splog, s = bz & (nsp - 1);
    const int bh = b * NH + h, sbh = s * 8 + bh;
    const _Float16* kp = kT + (size_t)bh * N_ * D_;
    const _Float16* vp = vB + (size_t)bh * D_ * N_;
    const int lane = t & 63, w = t >> 6, l32 = lane & 31, hl = lane >> 5;
    const int srow = t >> 3, scol = (t & 7) * 8;

    const _Float16* qp = qT + ((size_t)bh * N_ + qt * 128 + w * 32 + l32) * D_;
    f16x8 qf[4];
    #pragma unroll
    for (int kc = 0; kc < 4; ++kc) qf[kc] = *(const f16x8*)(qp + kc * 16 + hl * 8);

    f32x16 oacc0 = {}, oacc1 = {};
    float m_run = 0.f, l_run = 0.f;

    const int niter = 64 >> splog;
    const int jt_lo = s * niter, jt_hi = jt_lo + niter;
    f16x8 kpre[2], vpre[2];
    #pragma unroll
    for (int r = 0; r < 2; ++r) {
        int row = srow + r * 32;
        kpre[r] = *(const f16x8*)(kp + (size_t)(jt_lo * 64 + row) * D_ + scol);
        vpre[r] = *(const f16x8*)(vp + (size_t)row * N_ + jt_lo * 64 + scol);
    }

    for (int jt = jt_lo; jt < jt_hi; ++jt) {
        __syncthreads();
        #pragma unroll
        for (int r = 0; r < 2; ++r) {
            int row = srow + r * 32;
            *(f16x8*)&sm.s.K[row][scol] = kpre[r];
            *(f16x8*)&sm.s.V[row][scol] = vpre[r];
        }
        __syncthreads();
        if (jt + 1 < jt_hi) {
            #pragma unroll
            for (int r = 0; r < 2; ++r) {
                int row = srow + r * 32;
                kpre[r] = *(const f16x8*)(kp + (size_t)((jt + 1) * 64 + row) * D_ + scol);
                vpre[r] = *(const f16x8*)(vp + (size_t)row * N_ + (jt + 1) * 64 + scol);
            }
        }
        f32x16 sa0 = {}, sa1 = {};
        #pragma unroll
        for (int kc = 0; kc < 4; ++kc) {
            f16x8 kf0 = *(const f16x8*)&sm.s.K[l32][kc * 16 + hl * 8];
            sa0 = __builtin_amdgcn_mfma_f32_32x32x16_f16(kf0, qf[kc], sa0, 0, 0, 0);
            f16x8 kf1 = *(const f16x8*)&sm.s.K[32 + l32][kc * 16 + hl * 8];
            sa1 = __builtin_amdgcn_mfma_f32_32x32x16_f16(kf1, qf[kc], sa1, 0, 0, 0);
        }
        if (jt == jt_lo) {
            f32x16 mm;
            #pragma unroll
            for (int r = 0; r < 16; ++r) mm[r] = fmaxf(sa0[r], sa1[r]);
            f32x4 m4;
            #pragma unroll
            for (int r = 0; r < 4; ++r)
                m4[r] = fmaxf(fmaxf(mm[r], mm[r + 4]), fmaxf(mm[r + 8], mm[r + 12]));
            float mx = fmaxf(fmaxf(m4[0], m4[1]), fmaxf(m4[2], m4[3]));
            mx = fmaxf(mx, __shfl_xor(mx, 32));
            m_run = mx + 8.0f;
        }
        #pragma unroll
        for (int r = 0; r < 16; ++r) sa0[r] = __builtin_amdgcn_exp2f(sa0[r] - m_run);
        #pragma unroll
        for (int r = 0; r < 16; ++r) sa1[r] = __builtin_amdgcn_exp2f(sa1[r] - m_run);
        f32x16 sv = sa0 + sa1;
        f32x4 s4;
        #pragma unroll
        for (int r = 0; r < 4; ++r) s4[r] = (sv[r] + sv[r + 4]) + (sv[r + 8] + sv[r + 12]);
        float rs = (s4[0] + s4[1]) + (s4[2] + s4[3]);
        rs += __shfl_xor(rs, 32);
        l_run += rs;
        #pragma unroll
        for (int jb = 0; jb < 2; ++jb) {
            const f32x16& sa = jb ? sa1 : sa0;
            union BU { f16x4 v; int d[2]; } bf[4];
            #pragma unroll
            for (int q = 0; q < 8; ++q)
                bf[q >> 1].d[q & 1] =
                    __builtin_bit_cast(int, __builtin_amdgcn_cvt_pkrtz(sa[2 * q], sa[2 * q + 1]));
            #pragma unroll
            for (int c = 0; c < 4; ++c) {
                const int vcol = jb * 32 + c * 8 + hl * 4;
                f16x4 va = *(const f16x4*)&sm.s.V[l32][vcol];
                oacc0 = __builtin_amdgcn_mfma_f32_32x32x8f16(va, bf[c].v, oacc0, 0, 0, 0);
                f16x4 vb = *(const f16x4*)&sm.s.V[32 + l32][vcol];
                oacc1 = __builtin_amdgcn_mfma_f32_32x32x8f16(vb, bf[c].v, oacc1, 0, 0, 0);
            }
        }
    }
    float linv = 1.f / l_run;
    if (hl == 0) {
        mpart[(size_t)sbh * N_ + qt * 128 + w * 32 + l32] = m_run;
        lpart[(size_t)sbh * N_ + qt * 128 + w * 32 + l32] = l_run;
    }
    __syncthreads();
    #pragma unroll
    for (int db = 0; db < 2; ++db) {
        const f32x16& oc = db ? oacc1 : oacc0;
        #pragma unroll
        for (int rq = 0; rq < 4; ++rq) {
            f16x4 pv = { (_Float16)(oc[rq * 4 + 0] * linv), (_Float16)(oc[rq * 4 + 1] * linv),
                         (_Float16)(oc[rq * 4 + 2] * linv), (_Float16)(oc[rq * 4 + 3] * linv) };
            *(f16x4*)&sm.Os[w * 32 + l32][db * 32 + rq * 8 + hl * 4] = pv;
        }
    }
    __syncthreads();
    _Float16* op = opart + ((size_t)sbh * N_ + qt * 128) * D_;
    #pragma unroll
    for (int r = 0; r < 4; ++r) {
        int idx = r * 256 + t;
        int i = idx >> 3, ch = (idx & 7) * 8;
        *(f16x8*)(op + (size_t)i * D_ + ch) = *(const f16x8*)&sm.Os[i][ch];
    }
}

// ---------------------------------------------------------------------------
// Projection + FUSED combine (EXACT r4 verified config): n-major, n-tile 32,
// block = [128 c x 32 n]; grid(128,2,2) = 512 = 2/CU; staged A with 2
// barriers per k-step. Epilogue: bias + x.
// ---------------------------------------------------------------------------
__global__ __launch_bounds__(256) void projc_gemm(const _Float16* __restrict__ opart,
                                                  const float* __restrict__ mpart,
                                                  const float* __restrict__ lpart,
                                                  const _Float16* __restrict__ w_outT,
                                                  const float* __restrict__ b_out,
                                                  const float* __restrict__ x,
                                                  float* __restrict__ out) {
    __shared__ __align__(16) union SMP {
        struct {
            _Float16 Y[32][264];                       // 16896 B (n x k, pad 8)
            union { float W[4][32][4]; _Float16 A[128][40]; } u;  // 10240 B
        } p;
        float Os[128][36];                             // 18432 B (epilogue)
    } sm;
    const int nt = blockIdx.x, chh = blockIdx.y, b = blockIdx.z;
    const int n0 = nt * 32, c0 = chh * 128;
    const int t = threadIdx.x;
    const int lane = t & 63, w = t >> 6, quad = lane >> 4, l16 = lane & 15;

    // phase 0: combine weights W[h][n][s] for this 32-n strip (threads <128)
    if (t < 128) {
        const int nl = t & 31, hh = t >> 5;
        const int bh = b * NH + hh;
        float mv[4], lv[4];
        #pragma unroll
        for (int sI = 0; sI < 4; ++sI) {
            mv[sI] = mpart[(size_t)(sI * 8 + bh) * N_ + n0 + nl];
            lv[sI] = lpart[(size_t)(sI * 8 + bh) * N_ + n0 + nl];
        }
        float M = fmaxf(fmaxf(mv[0], mv[1]), fmaxf(mv[2], mv[3]));
        float ws[4], sum = 0.f;
        #pragma unroll
        for (int sI = 0; sI < 4; ++sI) {
            ws[sI] = __builtin_amdgcn_exp2f(mv[sI] - M) * lv[sI];
            sum += ws[sI];
        }
        float inv = 1.f / sum;
        #pragma unroll
        for (int sI = 0; sI < 4; ++sI) sm.p.u.W[hh][nl][sI] = ws[sI] * inv;
    }
    __syncthreads();

    // phase 1: combine 4 split streams -> Y[n][k] f16 (once per block)
    #pragma unroll
    for (int it = 0; it < 4; ++it) {
        int idx = it * 256 + t;
        int n = idx >> 5, kg = (idx & 31) * 8;
        int hh = kg >> 6, d0 = kg & 63;
        const int bh = b * NH + hh;
        const float* Wn = &sm.p.u.W[hh][n][0];
        float accf[8] = {};
        #pragma unroll
        for (int sI = 0; sI < 4; ++sI) {
            f16x8 ov = *(const f16x8*)(opart + ((size_t)(sI * 8 + bh) * N_ + n0 + n) * D_ + d0);
            float wsv = Wn[sI];
            #pragma unroll
            for (int j = 0; j < 8; ++j) accf[j] += wsv * (float)ov[j];
        }
        f16x8 yv;
        #pragma unroll
        for (int j = 0; j < 8; ++j) yv[j] = (_Float16)accf[j];
        *(f16x8*)&sm.p.Y[n][kg] = yv;
    }
    __syncthreads();

    // phase 2: GEMM: 128c x 32n, k-loop over 256. Wave w owns c-blocks 2w,2w+1.
    const int srow = t >> 1, skoff = (t & 1) * 16;   // A stage: 128 rows x 32 k
    const _Float16* ap = w_outT + (size_t)(c0 + srow) * C_ + skoff;
    f16x8 apre0 = *(const f16x8*)(ap);
    f16x8 apre1 = *(const f16x8*)(ap + 8);
    f32x4 acc[2][2] = {};
    for (int k0 = 0; k0 < C_; k0 += 32) {
        __syncthreads();
        *(f16x8*)&sm.p.u.A[srow][skoff]     = apre0;
        *(f16x8*)&sm.p.u.A[srow][skoff + 8] = apre1;
        __syncthreads();
        if (k0 + 32 < C_) {
            apre0 = *(const f16x8*)(ap + k0 + 32);
            apre1 = *(const f16x8*)(ap + k0 + 40);
        }
        #pragma unroll
        for (int cb = 0; cb < 2; ++cb) {
            f16x8 af = *(const f16x8*)&sm.p.u.A[w * 32 + cb * 16 + l16][quad * 8];
            #pragma unroll
            for (int nb = 0; nb < 2; ++nb) {
                f16x8 bf = *(const f16x8*)&sm.p.Y[nb * 16 + l16][k0 + quad * 8];
                acc[cb][nb] = __builtin_amdgcn_mfma_f32_16x16x32_f16(af, bf, acc[cb][nb], 0, 0, 0);
            }
        }
    }
    __syncthreads();   // Y/A dead; Os aliases them
    #pragma unroll
    for (int cb = 0; cb < 2; ++cb)
        #pragma unroll
        for (int nb = 0; nb < 2; ++nb)
            #pragma unroll
            for (int rg = 0; rg < 4; ++rg)
                sm.Os[w * 32 + cb * 16 + quad * 4 + rg][nb * 16 + l16] =
                    acc[cb][nb][rg] + b_out[c0 + w * 32 + cb * 16 + quad * 4 + rg];
    __syncthreads();
    const float* xp = x + ((size_t)b * C_ + c0) * N_ + n0;
    float* op = out + ((size_t)b * C_ + c0) * N_ + n0;
    #pragma unroll
    for (int r = 0; r < 4; ++r) {
        int idx = r * 256 + t;
        int c = idx >> 3, ng = (idx & 7) * 4;
        f32x4 v  = *(const f32x4*)&sm.Os[c][ng];
        f32x4 xv = *(const f32x4*)(xp + (size_t)c * N_ + ng);
        f32x4 o  = { v[0] + xv[0], v[1] + xv[1], v[2] + xv[2], v[3] + xv[3] };
        *(f32x4*)(op + (size_t)c * N_ + ng) = o;
    }
}

// ---------------------------------------------------------------------------
// Workspace (f16 element offsets), nsp=4 (~35 MB):
//   xT 0 (2,097,152) | w_outT 2,293,760 (65,536)
//   qT 2,359,296 | kT 4,456,448 | vB 6,553,600 (2,097,152 each)
//   opart 8,650,752 (8,388,608) | mpart f32 after | lpart after
// ---------------------------------------------------------------------------
extern "C" void kernel_launch(void* const* d_in, const int* in_sizes, int n_in,
                              void* d_out, int out_size, void* d_ws, size_t ws_size,
                              hipStream_t stream) {
    const float* x       = (const float*)d_in[0];
    const float* w_embed = (const float*)d_in[1];
    const float* b_embed = (const float*)d_in[2];
    const float* w_out   = (const float*)d_in[3];
    const float* b_out   = (const float*)d_in[4];
    float* out = (float*)d_out;

    const int splog = 2;   // nsp=4: attn 1024 blocks (flat, XCD-swizzled)

    _Float16* base   = (_Float16*)d_ws;
    _Float16* xT     = base;
    _Float16* w_outT = base + 2293760;
    _Float16* qT     = base + 2359296;
    _Float16* kT     = base + 4456448;
    _Float16* vB     = base + 6553600;
    _Float16* opart  = base + 8650752;
    float*    mpart  = (float*)(opart + (size_t)4 * 8 * N_ * D_);
    float*    lpart  = mpart + (size_t)4 * 8 * N_;

    prep_kernel<<<dim3(528, 1, 1), 256, 0, stream>>>(x, w_out, xT, w_outT);
    qkv_gemm   <<<dim3(64, 12, 2), 256, 0, stream>>>(xT, w_embed, b_embed, qT, kT, vB);
    attn_kernel<<<dim3(1024, 1, 1), 256, 0, stream>>>(qT, kT, vB, opart, mpart, lpart, splog);
    projc_gemm <<<dim3(128, 2, 2), 256, 0, stream>>>(opart, mpart, lpart, w_outT, b_out, x, out);
}